// Round 7
// baseline (262.349 us; speedup 1.0000x reference)
//
#include <hip/hip_runtime.h>
#include <hip/hip_bf16.h>

#define NN 100000
#define NE 1600000
#define NF 128
#define UU 64

typedef __attribute__((ext_vector_type(8))) short short8;
typedef __attribute__((ext_vector_type(4))) float f32x4;

// ---------------- workspace layout (bytes) ----------------
static const size_t OFF_FLAG = 0;                               // 256
static const size_t OFF_SRC  = 256;                             // NE*4
static const size_t OFF_H2   = OFF_SRC + (size_t)NE * 4;        // NN*64*2 (bf16, slice-major)
static const size_t OFF_AD   = OFF_H2  + (size_t)NN * UU * 2;   // NN*4
static const size_t OFF_AS   = OFF_AD  + (size_t)NN * 4;        // NN*4
static const size_t OFF_ROW  = OFF_AS  + (size_t)NN * 4;        // (NN+1)*4
static const size_t OFF_WP   = OFF_ROW + (size_t)(NN + 1) * 4;  // 8192 bf16 (16KB)
static const size_t OFF_W    = OFF_WP  + 16384;                 // NE*4 edge weights

__device__ __forceinline__ unsigned short bfr(float v) {
    unsigned u = __float_as_uint(v);
    return (unsigned short)((u + 0x7FFFu + ((u >> 16) & 1u)) >> 16);
}

// prep: edge-format flag + W packed into MFMA B-fragment-linear bf16 layout.
__global__ __launch_bounds__(256) void prep(const int* __restrict__ ew,
                                            const float* __restrict__ W,
                                            int* __restrict__ flag,
                                            unsigned short* __restrict__ Wp) {
    if (blockIdx.x == 0) {
        if (threadIdx.x == 0) {
            int a = ew[2 * 400000 + 1] | ew[2 * 800000 + 1] |
                    ew[2 * 1200000 + 1] | ew[2 * 1599999 + 1];
            *flag = (a == 0) ? 1 : 0;   // 1 => int64
        }
        return;
    }
    int i = (blockIdx.x - 1) * 256 + threadIdx.x;   // 32*256 = 8192
    int j   = i & 7;
    int l15 = (i >> 3) & 15;
    int quad = (i >> 7) & 3;
    int kb  = (i >> 9) & 3;
    int nt  = i >> 11;
    Wp[i] = bfr(W[(size_t)(kb * 32 + quad * 8 + j) * UU + nt * 16 + l15]);
}

#define GEMM_BLOCKS   1563  // ceil(NN/64)
#define ROWS_BLOCKS   391   // ceil((NN+1)/256)
#define UNPACK_BLOCKS 1563

__global__ __launch_bounds__(256) void mega(const float* __restrict__ X,
                                            const void* __restrict__ edges,
                                            const int* __restrict__ flag,
                                            const unsigned short* __restrict__ Wp,
                                            const float* __restrict__ ka,
                                            unsigned short* __restrict__ h2s,
                                            float* __restrict__ a_dst,
                                            float* __restrict__ a_src,
                                            int* __restrict__ src32,
                                            int* __restrict__ rows) {
    int bid = blockIdx.x;
    int tid = threadIdx.x;

    if (bid < GEMM_BLOCKS) {
        // ---- MFMA GEMM: h = X @ W. Block = 64 nodes (4 waves x 16). ----
        int wv = tid >> 6, lane = tid & 63;
        int quad = lane >> 4, l15 = lane & 15;
        int nb = bid * 64 + wv * 16;
        int row = nb + l15; if (row >= NN) row = NN - 1;   // clamped: stores guarded
        const float* xr = X + (size_t)row * NF + quad * 8;

        short8 afrag[4];
#pragma unroll
        for (int kb = 0; kb < 4; kb++) {
            float4 p0 = *(const float4*)(xr + kb * 32);
            float4 p1 = *(const float4*)(xr + kb * 32 + 4);
            short8 a;
            a[0] = (short)bfr(p0.x); a[1] = (short)bfr(p0.y);
            a[2] = (short)bfr(p0.z); a[3] = (short)bfr(p0.w);
            a[4] = (short)bfr(p1.x); a[5] = (short)bfr(p1.y);
            a[6] = (short)bfr(p1.z); a[7] = (short)bfr(p1.w);
            afrag[kb] = a;
        }

        f32x4 acc[4] = {f32x4{0,0,0,0}, f32x4{0,0,0,0}, f32x4{0,0,0,0}, f32x4{0,0,0,0}};
        const short8* wpf = (const short8*)Wp;
#pragma unroll
        for (int nt = 0; nt < 4; nt++) {
#pragma unroll
            for (int kb = 0; kb < 4; kb++) {
                short8 b = wpf[((nt * 4 + kb) * 4 + quad) * 16 + l15];
                acc[nt] = __builtin_amdgcn_mfma_f32_16x16x32_bf16(afrag[kb], b, acc[nt], 0, 0, 0);
            }
        }

        float kad[4], kas[4];
#pragma unroll
        for (int nt = 0; nt < 4; nt++) {
            kad[nt] = ka[nt * 16 + l15];
            kas[nt] = ka[64 + nt * 16 + l15];
        }
        int sl2 = l15 >> 3, u8 = l15 & 7;   // slice within nt-pair, unit-in-slice
#pragma unroll
        for (int r = 0; r < 4; r++) {
            int m = nb + quad * 4 + r;
            if (m < NN) {
#pragma unroll
                for (int nt = 0; nt < 4; nt++) {
                    int slice = 2 * nt + sl2;   // unit = nt*16 + l15 = slice*8 + u8
                    h2s[((size_t)slice * NN + m) * 8 + u8] = bfr(acc[nt][r]);
                }
            }
            float pd = acc[0][r] * kad[0] + acc[1][r] * kad[1] + acc[2][r] * kad[2] + acc[3][r] * kad[3];
            float ps = acc[0][r] * kas[0] + acc[1][r] * kas[1] + acc[2][r] * kas[2] + acc[3][r] * kas[3];
            pd += __shfl_xor(pd, 1); pd += __shfl_xor(pd, 2);
            pd += __shfl_xor(pd, 4); pd += __shfl_xor(pd, 8);
            ps += __shfl_xor(ps, 1); ps += __shfl_xor(ps, 2);
            ps += __shfl_xor(ps, 4); ps += __shfl_xor(ps, 8);
            if (l15 == 0 && m < NN) { a_dst[m] = pd; a_src[m] = ps; }
        }
        return;
    }
    bid -= GEMM_BLOCKS;

    if (bid < ROWS_BLOCKS) {
        // ---- CSR row offsets by binary search on ORIGINAL edges ----
        int n = bid * 256 + tid;
        if (n > NN) return;
        if (n == NN) { rows[NN] = NE; return; }
        int fl = *flag;
        const int* ew = (const int*)edges;
        int lo = 0, hi = NE;
        while (lo < hi) {
            int mid = (lo + hi) >> 1;
            int d = fl ? ew[4 * (size_t)mid] : ew[2 * (size_t)mid];
            if (d < n) lo = mid + 1; else hi = mid;
        }
        rows[n] = lo;
        return;
    }
    bid -= ROWS_BLOCKS;

    // ---- unpack src (vectorized 16B reads) ----
    {
        int fl = *flag;
        if (fl) {
            const int4* ev = (const int4*)edges;   // one int4 per edge
#pragma unroll
            for (int t = 0; t < 4; t++) {
                int i = bid * 1024 + t * 256 + tid;
                if (i < NE) { int4 v = ev[i]; src32[i] = v.z; }
            }
        } else {
            const int4* ev = (const int4*)edges;   // one int4 per 2 edges
#pragma unroll
            for (int t = 0; t < 2; t++) {
                int p = bid * 512 + t * 256 + tid;
                if (p * 2 < NE) {
                    int4 v = ev[p];
                    *(int2*)(src32 + p * 2) = make_int2(v.y, v.w);
                }
            }
        }
    }
}

__device__ __forceinline__ float edge_score(float ad, float as) {
    float sc = ad + as;
    sc = sc > 0.f ? sc : 0.2f * sc;
    sc = fminf(fmaxf(sc, -2.f), 2.f);
    return __expf(sc);
}

// edge-parallel: w[e] = exp(clip(leakyrelu(a_dst[dst]+a_src[src])))
__global__ __launch_bounds__(256) void wkern(const void* __restrict__ edges,
                                             const int* __restrict__ flag,
                                             const float* __restrict__ a_dst,
                                             const float* __restrict__ a_src,
                                             float* __restrict__ w) {
    int fl = *flag;
    int tid = threadIdx.x;
    if (fl) {
        const int4* ev = (const int4*)edges;       // {dlo,dhi,slo,shi}
#pragma unroll
        for (int t = 0; t < 4; t++) {
            int i = blockIdx.x * 1024 + t * 256 + tid;
            if (i < NE) {
                int4 v = ev[i];
                w[i] = edge_score(a_dst[v.x], a_src[v.z]);
            }
        }
    } else {
        const int4* ev = (const int4*)edges;       // {d0,s0,d1,s1}
#pragma unroll
        for (int t = 0; t < 2; t++) {
            int p = blockIdx.x * 512 + t * 256 + tid;
            if (p * 2 < NE) {
                int4 v = ev[p];
                float2 wv = make_float2(edge_score(a_dst[v.x], a_src[v.y]),
                                        edge_score(a_dst[v.z], a_src[v.w]));
                *(float2*)(w + p * 2) = wv;
            }
        }
    }
}

// XCD-sliced aggregation: slice x = blockIdx&7 (rides the XCD round-robin;
// correctness independent of mapping). Each XCD's h-slice = 1.6 MB -> L2-resident.
// Wave = 4 nodes; per node: 16 groups x 4 lanes; group = 1 edge, lane q = 2 units.
__global__ __launch_bounds__(256) void aggregate(const int* __restrict__ rows,
                                                 const int* __restrict__ srcv,
                                                 const float* __restrict__ w,
                                                 const unsigned short* __restrict__ h2s,
                                                 float* __restrict__ out) {
    int x = blockIdx.x & 7;
    int g16 = blockIdx.x >> 3;
    int wv = threadIdx.x >> 6, lane = threadIdx.x & 63;
    int grp = lane >> 2, q = lane & 3;
    const unsigned short* hs = h2s + (size_t)x * NN * 8 + q * 2;
    int nbase = g16 * 16 + wv * 4;              // 6250*16 = 100000 exact

#pragma unroll
    for (int i = 0; i < 4; i++) {
        int n = nbase + i;
        int s = rows[n], e = rows[n + 1];
        int cnt = e - s;
        float a0 = 0.f, a1 = 0.f, ws = 0.f;
        for (int c = s; c < e; c += 16) {
            int j = c + grp;
            float wl = 0.f; int sj = 0;
            if (j < e) { wl = w[j]; sj = srcv[j]; }
            unsigned hh = *(const unsigned*)(hs + (size_t)sj * 8);
            a0 += wl * __uint_as_float(hh << 16);
            a1 += wl * __uint_as_float(hh & 0xFFFF0000u);
            ws += wl;
        }
        // reduce across the 16 edge-groups (lane bits 2..5)
#pragma unroll
        for (int off = 4; off <= 32; off <<= 1) {
            a0 += __shfl_xor(a0, off);
            a1 += __shfl_xor(a1, off);
            ws += __shfl_xor(ws, off);
        }
        float inv = (cnt > 0) ? 1.f / ws : 0.f;
        if (lane < 4)
            *(float2*)(out + (size_t)n * UU + x * 8 + q * 2) =
                make_float2(a0 * inv, a1 * inv);
    }
}

extern "C" void kernel_launch(void* const* d_in, const int* in_sizes, int n_in,
                              void* d_out, int out_size, void* d_ws, size_t ws_size,
                              hipStream_t stream) {
    const float* X  = (const float*)d_in[0];
    const void*  Ed = d_in[1];
    const float* W  = (const float*)d_in[2];
    const float* KA = (const float*)d_in[3];
    float* out = (float*)d_out;

    char* ws = (char*)d_ws;
    int*            flag  = (int*)(ws + OFF_FLAG);
    int*            src32 = (int*)(ws + OFF_SRC);
    unsigned short* h2s   = (unsigned short*)(ws + OFF_H2);
    float*          a_dst = (float*)(ws + OFF_AD);
    float*          a_src = (float*)(ws + OFF_AS);
    int*            rows  = (int*)(ws + OFF_ROW);
    unsigned short* Wp    = (unsigned short*)(ws + OFF_WP);
    float*          wbuf  = (float*)(ws + OFF_W);

    prep<<<33, 256, 0, stream>>>((const int*)Ed, W, flag, Wp);
    mega<<<GEMM_BLOCKS + ROWS_BLOCKS + UNPACK_BLOCKS, 256, 0, stream>>>(
        X, Ed, flag, Wp, KA, h2s, a_dst, a_src, src32, rows);
    wkern<<<1563, 256, 0, stream>>>(Ed, flag, a_dst, a_src, wbuf);
    aggregate<<<6250 * 8, 256, 0, stream>>>(rows, src32, wbuf, h2s, out);
}

// Round 8
// 160.109 us; speedup vs baseline: 1.6386x; 1.6386x over previous
//
#include <hip/hip_runtime.h>
#include <hip/hip_bf16.h>

#define NN 100000
#define NE 1600000
#define NF 128
#define UU 64

typedef __attribute__((ext_vector_type(8))) short short8;
typedef __attribute__((ext_vector_type(4))) float f32x4;

// ---------------- workspace layout (bytes) ----------------
static const size_t OFF_FLAG = 0;                               // 256
static const size_t OFF_SRC  = 256;                             // NE*4
static const size_t OFF_H2   = OFF_SRC + (size_t)NE * 4;        // NN*64*2 (bf16)
static const size_t OFF_AD   = OFF_H2  + (size_t)NN * UU * 2;   // NN*4
static const size_t OFF_AS   = OFF_AD  + (size_t)NN * 4;        // NN*4
static const size_t OFF_ROW  = OFF_AS  + (size_t)NN * 4;        // (NN+1)*4
static const size_t OFF_WP   = OFF_ROW + (size_t)(NN + 1) * 4;  // 8192 bf16 (16KB)

__device__ __forceinline__ unsigned short bfr(float v) {
    unsigned u = __float_as_uint(v);
    return (unsigned short)((u + 0x7FFFu + ((u >> 16) & 1u)) >> 16);
}

// prep: edge-format flag + W packed into MFMA B-fragment-linear bf16 layout.
// Parallel (block 0 = flag, blocks 1..32 = W pack): single-block version cost ~12 µs.
__global__ __launch_bounds__(256) void prep(const int* __restrict__ ew,
                                            const float* __restrict__ W,
                                            int* __restrict__ flag,
                                            unsigned short* __restrict__ Wp) {
    if (blockIdx.x == 0) {
        if (threadIdx.x == 0) {
            int a = ew[2 * 400000 + 1] | ew[2 * 800000 + 1] |
                    ew[2 * 1200000 + 1] | ew[2 * 1599999 + 1];
            *flag = (a == 0) ? 1 : 0;   // 1 => int64
        }
        return;
    }
    int i = (blockIdx.x - 1) * 256 + threadIdx.x;   // 32*256 = 8192
    int j   = i & 7;
    int l15 = (i >> 3) & 15;
    int quad = (i >> 7) & 3;
    int kb  = (i >> 9) & 3;
    int nt  = i >> 11;
    Wp[i] = bfr(W[(size_t)(kb * 32 + quad * 8 + j) * UU + nt * 16 + l15]);
}

#define GEMM_BLOCKS   1563  // ceil(NN/64)
#define ROWS_BLOCKS   391   // ceil((NN+1)/256)
#define UNPACK_BLOCKS 1563

__global__ __launch_bounds__(256) void mega(const float* __restrict__ X,
                                            const void* __restrict__ edges,
                                            const int* __restrict__ flag,
                                            const unsigned short* __restrict__ Wp,
                                            const float* __restrict__ ka,
                                            unsigned short* __restrict__ h2,
                                            float* __restrict__ a_dst,
                                            float* __restrict__ a_src,
                                            int* __restrict__ src32,
                                            int* __restrict__ rows) {
    int bid = blockIdx.x;
    int tid = threadIdx.x;

    if (bid < GEMM_BLOCKS) {
        // ---- MFMA GEMM: h = X @ W. Block = 64 nodes (4 waves x 16). ----
        int wv = tid >> 6, lane = tid & 63;
        int quad = lane >> 4, l15 = lane & 15;
        int nb = bid * 64 + wv * 16;
        int row = nb + l15; if (row >= NN) row = NN - 1;   // clamped: stores guarded
        const float* xr = X + (size_t)row * NF + quad * 8;

        short8 afrag[4];
#pragma unroll
        for (int kb = 0; kb < 4; kb++) {
            float4 p0 = *(const float4*)(xr + kb * 32);
            float4 p1 = *(const float4*)(xr + kb * 32 + 4);
            short8 a;
            a[0] = (short)bfr(p0.x); a[1] = (short)bfr(p0.y);
            a[2] = (short)bfr(p0.z); a[3] = (short)bfr(p0.w);
            a[4] = (short)bfr(p1.x); a[5] = (short)bfr(p1.y);
            a[6] = (short)bfr(p1.z); a[7] = (short)bfr(p1.w);
            afrag[kb] = a;
        }

        f32x4 acc[4] = {f32x4{0,0,0,0}, f32x4{0,0,0,0}, f32x4{0,0,0,0}, f32x4{0,0,0,0}};
        const short8* wpf = (const short8*)Wp;
#pragma unroll
        for (int nt = 0; nt < 4; nt++) {
#pragma unroll
            for (int kb = 0; kb < 4; kb++) {
                short8 b = wpf[((nt * 4 + kb) * 4 + quad) * 16 + l15];
                acc[nt] = __builtin_amdgcn_mfma_f32_16x16x32_bf16(afrag[kb], b, acc[nt], 0, 0, 0);
            }
        }

        float kad[4], kas[4];
#pragma unroll
        for (int nt = 0; nt < 4; nt++) {
            kad[nt] = ka[nt * 16 + l15];
            kas[nt] = ka[64 + nt * 16 + l15];
        }
#pragma unroll
        for (int r = 0; r < 4; r++) {
            int m = nb + quad * 4 + r;
            if (m < NN) {
#pragma unroll
                for (int nt = 0; nt < 4; nt++)
                    h2[(size_t)m * UU + nt * 16 + l15] = bfr(acc[nt][r]);
            }
            float pd = acc[0][r] * kad[0] + acc[1][r] * kad[1] + acc[2][r] * kad[2] + acc[3][r] * kad[3];
            float ps = acc[0][r] * kas[0] + acc[1][r] * kas[1] + acc[2][r] * kas[2] + acc[3][r] * kas[3];
            pd += __shfl_xor(pd, 1); pd += __shfl_xor(pd, 2);
            pd += __shfl_xor(pd, 4); pd += __shfl_xor(pd, 8);
            ps += __shfl_xor(ps, 1); ps += __shfl_xor(ps, 2);
            ps += __shfl_xor(ps, 4); ps += __shfl_xor(ps, 8);
            if (l15 == 0 && m < NN) { a_dst[m] = pd; a_src[m] = ps; }
        }
        return;
    }
    bid -= GEMM_BLOCKS;

    if (bid < ROWS_BLOCKS) {
        // ---- CSR row offsets by binary search on ORIGINAL edges ----
        int n = bid * 256 + tid;
        if (n > NN) return;
        if (n == NN) { rows[NN] = NE; return; }
        int fl = *flag;
        const int* ew = (const int*)edges;
        int lo = 0, hi = NE;
        while (lo < hi) {
            int mid = (lo + hi) >> 1;
            int d = fl ? ew[4 * (size_t)mid] : ew[2 * (size_t)mid];
            if (d < n) lo = mid + 1; else hi = mid;
        }
        rows[n] = lo;
        return;
    }
    bid -= ROWS_BLOCKS;

    // ---- unpack src (vectorized 16B reads) ----
    {
        int fl = *flag;
        if (fl) {
            const int4* ev = (const int4*)edges;   // one int4 per edge: {dlo,dhi,slo,shi}
#pragma unroll
            for (int t = 0; t < 4; t++) {
                int i = bid * 1024 + t * 256 + tid;
                if (i < NE) { int4 v = ev[i]; src32[i] = v.z; }
            }
        } else {
            const int4* ev = (const int4*)edges;   // one int4 per 2 edges: {d0,s0,d1,s1}
#pragma unroll
            for (int t = 0; t < 2; t++) {
                int p = bid * 512 + t * 256 + tid;
                if (p * 2 < NE) {
                    int4 v = ev[p];
                    *(int2*)(src32 + p * 2) = make_int2(v.y, v.w);
                }
            }
        }
    }
}

__device__ __forceinline__ float edge_score(float ad, float as) {
    float sc = ad + as;
    sc = sc > 0.f ? sc : 0.2f * sc;
    sc = fminf(fmaxf(sc, -2.f), 2.f);
    return __expf(sc);
}

// One wave per node. 4 groups of 16 lanes; group gathers one edge's h row
// (uint2 = 4 bf16 feats/lane, 128 B/edge). Loads 4-deep batched with exact
// 1..4 tail. Measured 52.3 µs (R5) — best of all variants tried.
__global__ __launch_bounds__(256) void aggregate(const int* __restrict__ rows,
                                                 const int* __restrict__ srcv,
                                                 const unsigned short* __restrict__ h2,
                                                 const float* __restrict__ a_dst,
                                                 const float* __restrict__ a_src,
                                                 float* __restrict__ out) {
    int gid = blockIdx.x * blockDim.x + threadIdx.x;
    int n = gid >> 6;
    int lane = gid & 63;
    if (n >= NN) return;
    int s = rows[n], e = rows[n + 1];
    int cnt = e - s;
    float ad = a_dst[n];
    int g = lane >> 4, gl = lane & 15;
    const unsigned short* h2g = h2 + gl * 4;
    float4 acc = make_float4(0.f, 0.f, 0.f, 0.f);

#define GBATCH(C0, N)                                                            \
    {                                                                            \
        uint2 rr[4]; float sw[4]; int sjv[4];                                    \
        _Pragma("unroll")                                                        \
        for (int t = 0; t < (N); t++) {                                          \
            int j = (C0) + t * 4 + g;                                            \
            sjv[t] = __shfl(mysrc, j);                                           \
            sw[t]  = __shfl(myscore, j);                                         \
        }                                                                        \
        _Pragma("unroll")                                                        \
        for (int t = 0; t < (N); t++)                                            \
            rr[t] = *(const uint2*)(h2g + (size_t)sjv[t] * UU);                  \
        _Pragma("unroll")                                                        \
        for (int t = 0; t < (N); t++) {                                          \
            acc.x += sw[t] * __uint_as_float(rr[t].x << 16);                     \
            acc.y += sw[t] * __uint_as_float(rr[t].x & 0xFFFF0000u);             \
            acc.z += sw[t] * __uint_as_float(rr[t].y << 16);                     \
            acc.w += sw[t] * __uint_as_float(rr[t].y & 0xFFFF0000u);             \
        }                                                                        \
    }

    float inv;
    if (cnt <= 64) {
        int idx = s + lane;
        int mysrc = 0; float myscore = 0.f;
        if (idx < e) { mysrc = srcv[idx]; myscore = edge_score(ad, a_src[mysrc]); }
        int c = 0;
        for (; c + 16 <= cnt; c += 16) GBATCH(c, 4);
        int rem = cnt - c;                 // 0..15
        if (rem > 12)     GBATCH(c, 4)
        else if (rem > 8) GBATCH(c, 3)
        else if (rem > 4) GBATCH(c, 2)
        else if (rem > 0) GBATCH(c, 1);
        float t = myscore;
#pragma unroll
        for (int off = 32; off; off >>= 1) t += __shfl_xor(t, off);
        inv = (cnt > 0) ? 1.f / t : 0.f;
    } else {
        float ssum = 0.f;
        for (int i = s + lane; i < e; i += 64) ssum += edge_score(ad, a_src[srcv[i]]);
#pragma unroll
        for (int off = 32; off; off >>= 1) ssum += __shfl_xor(ssum, off);
        inv = 1.f / ssum;
        for (int c0 = s; c0 < e; c0 += 64) {
            int i = c0 + lane;
            int mysrc = 0; float myscore = 0.f;
            if (i < e) { mysrc = srcv[i]; myscore = edge_score(ad, a_src[mysrc]); }
            GBATCH(0, 4); GBATCH(16, 4); GBATCH(32, 4); GBATCH(48, 4);
        }
    }
#undef GBATCH

    acc.x += __shfl_xor(acc.x, 32); acc.y += __shfl_xor(acc.y, 32);
    acc.z += __shfl_xor(acc.z, 32); acc.w += __shfl_xor(acc.w, 32);
    acc.x += __shfl_xor(acc.x, 16); acc.y += __shfl_xor(acc.y, 16);
    acc.z += __shfl_xor(acc.z, 16); acc.w += __shfl_xor(acc.w, 16);
    if (lane < 16) {
        float4 o = make_float4(acc.x * inv, acc.y * inv, acc.z * inv, acc.w * inv);
        *(float4*)(out + (size_t)n * UU + gl * 4) = o;
    }
}

extern "C" void kernel_launch(void* const* d_in, const int* in_sizes, int n_in,
                              void* d_out, int out_size, void* d_ws, size_t ws_size,
                              hipStream_t stream) {
    const float* X  = (const float*)d_in[0];
    const void*  Ed = d_in[1];
    const float* W  = (const float*)d_in[2];
    const float* KA = (const float*)d_in[3];
    float* out = (float*)d_out;

    char* ws = (char*)d_ws;
    int*            flag  = (int*)(ws + OFF_FLAG);
    int*            src32 = (int*)(ws + OFF_SRC);
    unsigned short* h2    = (unsigned short*)(ws + OFF_H2);
    float*          a_dst = (float*)(ws + OFF_AD);
    float*          a_src = (float*)(ws + OFF_AS);
    int*            rows  = (int*)(ws + OFF_ROW);
    unsigned short* Wp    = (unsigned short*)(ws + OFF_WP);

    prep<<<33, 256, 0, stream>>>((const int*)Ed, W, flag, Wp);
    mega<<<GEMM_BLOCKS + ROWS_BLOCKS + UNPACK_BLOCKS, 256, 0, stream>>>(
        X, Ed, flag, Wp, KA, h2, a_dst, a_src, src32, rows);
    aggregate<<<(NN * 64 + 255) / 256, 256, 0, stream>>>(rows, src32, h2, a_dst, a_src, out);
}

// Round 9
// 157.640 us; speedup vs baseline: 1.6642x; 1.0157x over previous
//
#include <hip/hip_runtime.h>
#include <hip/hip_bf16.h>

#define NN 100000
#define NE 1600000
#define NF 128
#define UU 64

typedef __attribute__((ext_vector_type(8))) short short8;
typedef __attribute__((ext_vector_type(4))) float f32x4;

// ---------------- workspace layout (bytes) ----------------
static const size_t OFF_FLAG = 0;                               // 256
static const size_t OFF_EW   = 256;                             // NE*8 {src,w}
static const size_t OFF_H2   = OFF_EW  + (size_t)NE * 8;        // NN*64*2 (bf16)
static const size_t OFF_AD   = OFF_H2  + (size_t)NN * UU * 2;   // NN*4
static const size_t OFF_AS   = OFF_AD  + (size_t)NN * 4;        // NN*4
static const size_t OFF_ROW  = OFF_AS  + (size_t)NN * 4;        // (NN+1)*4
static const size_t OFF_WP   = OFF_ROW + (size_t)(NN + 1) * 4;  // 8192 bf16 (16KB)

__device__ __forceinline__ unsigned short bfr(float v) {
    unsigned u = __float_as_uint(v);
    return (unsigned short)((u + 0x7FFFu + ((u >> 16) & 1u)) >> 16);
}

// prep: edge-format flag + W packed into MFMA B-fragment-linear bf16 layout.
__global__ __launch_bounds__(256) void prep(const int* __restrict__ ew,
                                            const float* __restrict__ W,
                                            int* __restrict__ flag,
                                            unsigned short* __restrict__ Wp) {
    if (blockIdx.x == 0) {
        if (threadIdx.x == 0) {
            int a = ew[2 * 400000 + 1] | ew[2 * 800000 + 1] |
                    ew[2 * 1200000 + 1] | ew[2 * 1599999 + 1];
            *flag = (a == 0) ? 1 : 0;   // 1 => int64
        }
        return;
    }
    int i = (blockIdx.x - 1) * 256 + threadIdx.x;   // 32*256 = 8192
    int j   = i & 7;
    int l15 = (i >> 3) & 15;
    int quad = (i >> 7) & 3;
    int kb  = (i >> 9) & 3;
    int nt  = i >> 11;
    Wp[i] = bfr(W[(size_t)(kb * 32 + quad * 8 + j) * UU + nt * 16 + l15]);
}

#define GEMM_BLOCKS   1563  // ceil(NN/64)
#define ROWS_BLOCKS   391   // ceil((NN+1)/256)

__global__ __launch_bounds__(256) void mega(const float* __restrict__ X,
                                            const void* __restrict__ edges,
                                            const int* __restrict__ flag,
                                            const unsigned short* __restrict__ Wp,
                                            const float* __restrict__ ka,
                                            unsigned short* __restrict__ h2,
                                            float* __restrict__ a_dst,
                                            float* __restrict__ a_src,
                                            int* __restrict__ rows) {
    int bid = blockIdx.x;
    int tid = threadIdx.x;

    if (bid < GEMM_BLOCKS) {
        // ---- MFMA GEMM: h = X @ W. Block = 64 nodes (4 waves x 16). ----
        int wv = tid >> 6, lane = tid & 63;
        int quad = lane >> 4, l15 = lane & 15;
        int nb = bid * 64 + wv * 16;
        int row = nb + l15; if (row >= NN) row = NN - 1;   // clamped: stores guarded
        const float* xr = X + (size_t)row * NF + quad * 8;

        short8 afrag[4];
#pragma unroll
        for (int kb = 0; kb < 4; kb++) {
            float4 p0 = *(const float4*)(xr + kb * 32);
            float4 p1 = *(const float4*)(xr + kb * 32 + 4);
            short8 a;
            a[0] = (short)bfr(p0.x); a[1] = (short)bfr(p0.y);
            a[2] = (short)bfr(p0.z); a[3] = (short)bfr(p0.w);
            a[4] = (short)bfr(p1.x); a[5] = (short)bfr(p1.y);
            a[6] = (short)bfr(p1.z); a[7] = (short)bfr(p1.w);
            afrag[kb] = a;
        }

        f32x4 acc[4] = {f32x4{0,0,0,0}, f32x4{0,0,0,0}, f32x4{0,0,0,0}, f32x4{0,0,0,0}};
        const short8* wpf = (const short8*)Wp;
#pragma unroll
        for (int nt = 0; nt < 4; nt++) {
#pragma unroll
            for (int kb = 0; kb < 4; kb++) {
                short8 b = wpf[((nt * 4 + kb) * 4 + quad) * 16 + l15];
                acc[nt] = __builtin_amdgcn_mfma_f32_16x16x32_bf16(afrag[kb], b, acc[nt], 0, 0, 0);
            }
        }

        float kad[4], kas[4];
#pragma unroll
        for (int nt = 0; nt < 4; nt++) {
            kad[nt] = ka[nt * 16 + l15];
            kas[nt] = ka[64 + nt * 16 + l15];
        }
#pragma unroll
        for (int r = 0; r < 4; r++) {
            int m = nb + quad * 4 + r;
            if (m < NN) {
#pragma unroll
                for (int nt = 0; nt < 4; nt++)
                    h2[(size_t)m * UU + nt * 16 + l15] = bfr(acc[nt][r]);
            }
            float pd = acc[0][r] * kad[0] + acc[1][r] * kad[1] + acc[2][r] * kad[2] + acc[3][r] * kad[3];
            float ps = acc[0][r] * kas[0] + acc[1][r] * kas[1] + acc[2][r] * kas[2] + acc[3][r] * kas[3];
            pd += __shfl_xor(pd, 1); pd += __shfl_xor(pd, 2);
            pd += __shfl_xor(pd, 4); pd += __shfl_xor(pd, 8);
            ps += __shfl_xor(ps, 1); ps += __shfl_xor(ps, 2);
            ps += __shfl_xor(ps, 4); ps += __shfl_xor(ps, 8);
            if (l15 == 0 && m < NN) { a_dst[m] = pd; a_src[m] = ps; }
        }
        return;
    }
    bid -= GEMM_BLOCKS;

    // ---- CSR row offsets by binary search on ORIGINAL edges ----
    {
        int n = bid * 256 + tid;
        if (n > NN) return;
        if (n == NN) { rows[NN] = NE; return; }
        int fl = *flag;
        const int* ew = (const int*)edges;
        int lo = 0, hi = NE;
        while (lo < hi) {
            int mid = (lo + hi) >> 1;
            int d = fl ? ew[4 * (size_t)mid] : ew[2 * (size_t)mid];
            if (d < n) lo = mid + 1; else hi = mid;
        }
        rows[n] = lo;
    }
}

__device__ __forceinline__ float edge_score(float ad, float as) {
    float sc = ad + as;
    sc = sc > 0.f ? sc : 0.2f * sc;
    sc = fminf(fmaxf(sc, -2.f), 2.f);
    return __expf(sc);
}

// edge-parallel: ew8[e] = {src_e, w_e}; w_e = exp(clip(leakyrelu(a_dst[dst]+a_src[src])))
// Removes the a_src gather + exp from aggregate's per-wave dependent chain.
__global__ __launch_bounds__(256) void wkern(const void* __restrict__ edges,
                                             const int* __restrict__ flag,
                                             const float* __restrict__ a_dst,
                                             const float* __restrict__ a_src,
                                             int2* __restrict__ ew8) {
    int fl = *flag;
    int tid = threadIdx.x;
    if (fl) {
        const int4* ev = (const int4*)edges;       // {dlo,dhi,slo,shi}
#pragma unroll
        for (int t = 0; t < 4; t++) {
            int i = blockIdx.x * 1024 + t * 256 + tid;
            if (i < NE) {
                int4 v = ev[i];
                float w = edge_score(a_dst[v.x], a_src[v.z]);
                ew8[i] = make_int2(v.z, __float_as_int(w));
            }
        }
    } else {
        const int4* ev = (const int4*)edges;       // {d0,s0,d1,s1}
#pragma unroll
        for (int t = 0; t < 2; t++) {
            int p = blockIdx.x * 512 + t * 256 + tid;
            if (p * 2 < NE) {
                int4 v = ev[p];
                float w0 = edge_score(a_dst[v.x], a_src[v.y]);
                float w1 = edge_score(a_dst[v.z], a_src[v.w]);
                int4 o = make_int4(v.y, __float_as_int(w0), v.w, __float_as_int(w1));
                *(int4*)(ew8 + p * 2) = o;
            }
        }
    }
}

// One wave per node. Chain: rows -> ew8 (8B: src+weight) -> h-gather -> reduce.
// Gather: 4 groups x 16 lanes, uint2/lane (128 B/edge), 4-deep batched, exact tail.
__global__ __launch_bounds__(256) void aggregate(const int* __restrict__ rows,
                                                 const int2* __restrict__ ew8,
                                                 const unsigned short* __restrict__ h2,
                                                 float* __restrict__ out) {
    int gid = blockIdx.x * blockDim.x + threadIdx.x;
    int n = gid >> 6;
    int lane = gid & 63;
    if (n >= NN) return;
    int s = rows[n], e = rows[n + 1];
    int cnt = e - s;
    int g = lane >> 4, gl = lane & 15;
    const unsigned short* h2g = h2 + gl * 4;
    float4 acc = make_float4(0.f, 0.f, 0.f, 0.f);

#define GBATCH(C0, N)                                                            \
    {                                                                            \
        uint2 rr[4]; float sw[4]; int sjv[4];                                    \
        _Pragma("unroll")                                                        \
        for (int t = 0; t < (N); t++) {                                          \
            int j = (C0) + t * 4 + g;                                            \
            sjv[t] = __shfl(mysrc, j);                                           \
            sw[t]  = __shfl(myw, j);                                             \
        }                                                                        \
        _Pragma("unroll")                                                        \
        for (int t = 0; t < (N); t++)                                            \
            rr[t] = *(const uint2*)(h2g + (size_t)sjv[t] * UU);                  \
        _Pragma("unroll")                                                        \
        for (int t = 0; t < (N); t++) {                                          \
            acc.x += sw[t] * __uint_as_float(rr[t].x << 16);                     \
            acc.y += sw[t] * __uint_as_float(rr[t].x & 0xFFFF0000u);             \
            acc.z += sw[t] * __uint_as_float(rr[t].y << 16);                     \
            acc.w += sw[t] * __uint_as_float(rr[t].y & 0xFFFF0000u);             \
        }                                                                        \
    }

    float inv;
    if (cnt <= 64) {
        int idx = s + lane;
        int mysrc = 0; float myw = 0.f;
        if (idx < e) { int2 p = ew8[idx]; mysrc = p.x; myw = __int_as_float(p.y); }
        int c = 0;
        for (; c + 16 <= cnt; c += 16) GBATCH(c, 4);
        int rem = cnt - c;                 // 0..15
        if (rem > 12)     GBATCH(c, 4)
        else if (rem > 8) GBATCH(c, 3)
        else if (rem > 4) GBATCH(c, 2)
        else if (rem > 0) GBATCH(c, 1);
        float t = myw;
#pragma unroll
        for (int off = 32; off; off >>= 1) t += __shfl_xor(t, off);
        inv = (cnt > 0) ? 1.f / t : 0.f;
    } else {
        float ssum = 0.f;
        for (int i = s + lane; i < e; i += 64) ssum += __int_as_float(ew8[i].y);
#pragma unroll
        for (int off = 32; off; off >>= 1) ssum += __shfl_xor(ssum, off);
        inv = 1.f / ssum;
        for (int c0 = s; c0 < e; c0 += 64) {
            int i = c0 + lane;
            int mysrc = 0; float myw = 0.f;
            if (i < e) { int2 p = ew8[i]; mysrc = p.x; myw = __int_as_float(p.y); }
            GBATCH(0, 4); GBATCH(16, 4); GBATCH(32, 4); GBATCH(48, 4);
        }
    }
#undef GBATCH

    acc.x += __shfl_xor(acc.x, 32); acc.y += __shfl_xor(acc.y, 32);
    acc.z += __shfl_xor(acc.z, 32); acc.w += __shfl_xor(acc.w, 32);
    acc.x += __shfl_xor(acc.x, 16); acc.y += __shfl_xor(acc.y, 16);
    acc.z += __shfl_xor(acc.z, 16); acc.w += __shfl_xor(acc.w, 16);
    if (lane < 16) {
        float4 o = make_float4(acc.x * inv, acc.y * inv, acc.z * inv, acc.w * inv);
        *(float4*)(out + (size_t)n * UU + gl * 4) = o;
    }
}

extern "C" void kernel_launch(void* const* d_in, const int* in_sizes, int n_in,
                              void* d_out, int out_size, void* d_ws, size_t ws_size,
                              hipStream_t stream) {
    const float* X  = (const float*)d_in[0];
    const void*  Ed = d_in[1];
    const float* W  = (const float*)d_in[2];
    const float* KA = (const float*)d_in[3];
    float* out = (float*)d_out;

    char* ws = (char*)d_ws;
    int*            flag  = (int*)(ws + OFF_FLAG);
    int2*           ew8   = (int2*)(ws + OFF_EW);
    unsigned short* h2    = (unsigned short*)(ws + OFF_H2);
    float*          a_dst = (float*)(ws + OFF_AD);
    float*          a_src = (float*)(ws + OFF_AS);
    int*            rows  = (int*)(ws + OFF_ROW);
    unsigned short* Wp    = (unsigned short*)(ws + OFF_WP);

    prep<<<33, 256, 0, stream>>>((const int*)Ed, W, flag, Wp);
    mega<<<GEMM_BLOCKS + ROWS_BLOCKS, 256, 0, stream>>>(
        X, Ed, flag, Wp, KA, h2, a_dst, a_src, rows);
    wkern<<<1563, 256, 0, stream>>>(Ed, flag, a_dst, a_src, ew8);
    aggregate<<<(NN * 64 + 255) / 256, 256, 0, stream>>>(rows, ew8, h2, out);
}